// Round 4
// baseline (126.652 us; speedup 1.0000x reference)
//
#include <hip/hip_runtime.h>
#include <hip/hip_bf16.h>
#include <math.h>

// Problem constants
#define B2      128
#define NSEQ    256
#define DMODEL  256
#define NHEAD   8
#define CDIM    32
#define HC      256
#define NROWS   (B2*NSEQ)    // 32768
#define SCALING 0.17677669529663687f  // 1/sqrt(32)

typedef __attribute__((ext_vector_type(8))) short bf16x8;
typedef __attribute__((ext_vector_type(4))) float f32x4;

static __device__ __forceinline__ ushort f2bf(float f) {
    __hip_bfloat16 b = __float2bfloat16(f);
    ushort r; __builtin_memcpy(&r, &b, 2); return r;
}
static __device__ __forceinline__ float bf2f(ushort u) {
    __hip_bfloat16 b; __builtin_memcpy(&b, &u, 2); return __bfloat162float(b);
}
static __device__ __forceinline__ void gload_lds16(const void* g, void* l) {
    __builtin_amdgcn_global_load_lds((const __attribute__((address_space(1))) void*)g,
                                     (__attribute__((address_space(3))) void*)l, 16, 0, 0);
}

// ---------------- Kernel 0: fp32 -> bf16 conversion ----------------
// X, Wqkv (q-rows pre-scaled by 1/sqrt(C)) + Wg -> combined [1024][256], Wo.
__global__ __launch_bounds__(256) void convert_kernel(
    const float* __restrict__ X, const float* __restrict__ Wqkv,
    const float* __restrict__ Wg, const float* __restrict__ Wo,
    ushort* __restrict__ xb, ushort* __restrict__ wqkvgb, ushort* __restrict__ wob)
{
    const int NX = 8388608 / 4, NQ = 196608 / 4, NG = 65536 / 4, NO = 65536 / 4;
    const int total = NX + NQ + NG + NO;
    for (int idx = blockIdx.x * 256 + threadIdx.x; idx < total; idx += gridDim.x * 256) {
        const float* src; ushort* dst; int off; float scale = 1.0f;
        if (idx < NX)                { src = X;    dst = xb;              off = idx; }
        else if (idx < NX + NQ)      { src = Wqkv; dst = wqkvgb;          off = idx - NX;
                                       if (off < 16384) scale = SCALING; }   // q rows 0..255
        else if (idx < NX + NQ + NG) { src = Wg;   dst = wqkvgb + 196608; off = idx - NX - NQ; }
        else                         { src = Wo;   dst = wob;             off = idx - NX - NQ - NG; }
        float4 v = ((const float4*)src)[off];
        union { ushort u[4]; uint2 q; } p;
        p.u[0] = f2bf(v.x * scale); p.u[1] = f2bf(v.y * scale);
        p.u[2] = f2bf(v.z * scale); p.u[3] = f2bf(v.w * scale);
        *(uint2*)(dst + (size_t)off * 4) = p.q;
    }
}

// ---------------- Kernel 1: MFMA QKV+gate projection (swapped operands) ----
// D[e][m] = sum_k W[e][k] X[m][k].  A-frag = W rows (e), B-frag = X rows (m).
// Thread holds 4 consecutive e per (i,j) -> vectorized uint2 bf16 stores into
// per-head q/k/v layout. LDS k-chunk XOR swizzle (pre-swizzled global src).
__global__ __launch_bounds__(256) void qkvg_mfma_kernel(
    const ushort* __restrict__ Xb,     // bf16 [32768][256]
    const ushort* __restrict__ Wb,     // bf16 [1024][256] (q rows pre-scaled)
    const float* __restrict__ gbias,   // [256]
    ushort* __restrict__ q_ws,         // bf16 [128*8][256][32]
    ushort* __restrict__ k_ws,
    ushort* __restrict__ v_ws,
    ushort* __restrict__ g_ws)         // bf16 [32768][256]
{
    __shared__ ushort Als[128 * 32];   // W tile (e rows)    8KB
    __shared__ ushort Bls[128 * 32];   // X tile (m rows)    8KB

    const int tid  = threadIdx.x;
    const int w    = tid >> 6;
    const int lane = tid & 63;
    const int lj   = lane & 15;
    const int lg   = lane >> 4;
    const int wm   = w >> 1;           // e 64-block
    const int wn   = w & 1;            // m 64-block
    const int m0   = blockIdx.x * 128;
    const int nb   = blockIdx.y;       // 0..7 over 1024 e-cols
    const int e0   = nb * 128;

    f32x4 acc[4][4];
    #pragma unroll
    for (int i = 0; i < 4; ++i)
        #pragma unroll
        for (int j = 0; j < 4; ++j) acc[i][j] = (f32x4){0.f, 0.f, 0.f, 0.f};

    // staging lane constants (pre-swizzled global k-chunk, rule #21)
    const int srow = lane >> 2;                          // row within 16-chunk
    const int scol = (((lane & 3) ^ ((lane >> 3) & 3)) << 3);  // swizzled k elem
    // reader swizzle slot
    const int xsl = ((lg ^ ((lj >> 1) & 3)) << 3);

    for (int k0 = 0; k0 < 256; k0 += 32) {
        #pragma unroll
        for (int c = 0; c < 2; ++c) {
            const int ci = w * 2 + c;
            gload_lds16(Wb + (size_t)(e0 + ci * 16 + srow) * 256 + k0 + scol,
                        (char*)Als + ci * 1024);
            gload_lds16(Xb + (size_t)(m0 + ci * 16 + srow) * 256 + k0 + scol,
                        (char*)Bls + ci * 1024);
        }
        __syncthreads();
        bf16x8 af[4], bfr[4];
        #pragma unroll
        for (int i = 0; i < 4; ++i)
            af[i] = *(const bf16x8*)(Als + (wm * 64 + i * 16 + lj) * 32 + xsl);
        #pragma unroll
        for (int j = 0; j < 4; ++j)
            bfr[j] = *(const bf16x8*)(Bls + (wn * 64 + j * 16 + lj) * 32 + xsl);
        #pragma unroll
        for (int i = 0; i < 4; ++i)
            #pragma unroll
            for (int j = 0; j < 4; ++j)
                acc[i][j] = __builtin_amdgcn_mfma_f32_16x16x32_bf16(af[i], bfr[j], acc[i][j], 0, 0, 0);
        __syncthreads();
    }

    // epilogue: D row = e (4 consecutive per thread) -> uint2 stores
    const int seg = nb >> 1;           // 0=q 1=k 2=v 3=gate (block-uniform)
    #pragma unroll
    for (int i = 0; i < 4; ++i) {
        const int eb = (nb & 1) * 128 + wm * 64 + i * 16 + lg * 4;  // e within 256-seg
        const int h  = eb >> 5;
        const int c0 = eb & 31;
        #pragma unroll
        for (int j = 0; j < 4; ++j) {
            const int m  = m0 + wn * 64 + j * 16 + lj;
            const int b2 = m >> 8;
            const int n  = m & 255;
            union { ushort u[4]; uint2 v; } pk;
            if (seg < 3) {
                #pragma unroll
                for (int r = 0; r < 4; ++r) pk.u[r] = f2bf(acc[i][j][r]);
                ushort* base = (seg == 0) ? q_ws : (seg == 1) ? k_ws : v_ws;
                *(uint2*)(base + ((size_t)(b2 * 8 + h) * 256 + n) * 32 + c0) = pk.v;
            } else {
                #pragma unroll
                for (int r = 0; r < 4; ++r) {
                    const float z = acc[i][j][r] + gbias[eb + r];
                    pk.u[r] = f2bf(1.f / (1.f + __expf(-z)));
                }
                *(uint2*)(g_ws + (size_t)m * 256 + eb) = pk.v;
            }
        }
    }
}

// ---------------- Kernel 2: MFMA attention (unchanged) ----------------
#define SWZ(c) ((((c) >> 2) & 3) << 5)

__global__ __launch_bounds__(512) void attn_mfma_kernel(
    const ushort* __restrict__ q_ws,
    const ushort* __restrict__ k_ws,
    const ushort* __restrict__ v_ws,
    const ushort* __restrict__ g_ws,
    const float* __restrict__ bias,   // [8][256][256]
    const float* __restrict__ mask,   // [128][256]
    ushort* __restrict__ wa_ws)       // bf16 [32768][256]
{
    __shared__ ushort Ks[256 * 32];
    __shared__ ushort Vt[32 * 256];
    __shared__ ushort Pl[8 * 16 * 64];

    const int tid  = threadIdx.x;
    const int bh   = blockIdx.x >> 1;
    const int half = blockIdx.x & 1;
    const int b2   = bh >> 3;
    const int h    = bh & 7;
    const int w    = tid >> 6;
    const int lane = tid & 63;
    const int lj   = lane & 15;
    const int lg   = lane >> 4;

    {
        const uint4* gk = (const uint4*)(k_ws + (size_t)bh * 8192);
        uint4* sk = (uint4*)Ks;
        sk[tid]       = gk[tid];
        sk[tid + 512] = gk[tid + 512];
    }
    {
        const int cq = tid & 3;
        #pragma unroll
        for (int it = 0; it < 2; ++it) {
            const int n = it * 128 + (tid >> 2);
            uint4 v = *(const uint4*)(v_ws + (size_t)bh * 8192 + n * 32 + cq * 8);
            const ushort* pv = (const ushort*)&v;
            #pragma unroll
            for (int e = 0; e < 8; ++e) {
                const int c = cq * 8 + e;
                const int byte = c * 512 + ((2 * n) ^ SWZ(c));
                Vt[byte >> 1] = pv[e];
            }
        }
    }

    const int q0 = half * 128 + w * 16;
    const bf16x8 qf = *(const bf16x8*)(q_ws + (size_t)bh * 8192 + (size_t)(q0 + lj) * 32 + lg * 8);

    __syncthreads();

    f32x4 acc[16];
    const float* bbase = bias + (size_t)h * 256 * 256;
    const float* mrow  = mask + (size_t)b2 * 256;
    #pragma unroll
    for (int t = 0; t < 16; ++t) {
        const int col = t * 16 + lj;
        const float mterm = (mrow[col] - 1.0f) * 1e9f;
        #pragma unroll
        for (int r = 0; r < 4; ++r) {
            const int qrow = q0 + lg * 4 + r;
            acc[t][r] = bbase[(size_t)qrow * 256 + col] + mterm;
        }
    }

    #pragma unroll
    for (int t = 0; t < 16; ++t) {
        const bf16x8 kf = *(const bf16x8*)(Ks + (t * 16 + lj) * 32 + lg * 8);
        acc[t] = __builtin_amdgcn_mfma_f32_16x16x32_bf16(qf, kf, acc[t], 0, 0, 0);
    }

    float inv[4];
    #pragma unroll
    for (int r = 0; r < 4; ++r) {
        float m = acc[0][r];
        #pragma unroll
        for (int t = 1; t < 16; ++t) m = fmaxf(m, acc[t][r]);
        m = fmaxf(m, __shfl_xor(m, 1));
        m = fmaxf(m, __shfl_xor(m, 2));
        m = fmaxf(m, __shfl_xor(m, 4));
        m = fmaxf(m, __shfl_xor(m, 8));
        float s = 0.f;
        #pragma unroll
        for (int t = 0; t < 16; ++t) {
            float e = __expf(acc[t][r] - m);
            acc[t][r] = e;
            s += e;
        }
        s += __shfl_xor(s, 1);
        s += __shfl_xor(s, 2);
        s += __shfl_xor(s, 4);
        s += __shfl_xor(s, 8);
        inv[r] = 1.0f / s;
    }

    ushort* PlW = Pl + w * 1024;
    f32x4 o0 = {0.f, 0.f, 0.f, 0.f};
    f32x4 o1 = {0.f, 0.f, 0.f, 0.f};
    #pragma unroll
    for (int ch = 0; ch < 4; ++ch) {
        #pragma unroll
        for (int tt = 0; tt < 4; ++tt) {
            const int t = ch * 4 + tt;
            #pragma unroll
            for (int r = 0; r < 4; ++r) {
                const int row  = lg * 4 + r;
                const int byte = row * 128 + ((32 * tt + 2 * lj) ^ (lg << 5));
                PlW[byte >> 1] = f2bf(acc[t][r]);
            }
        }
        #pragma unroll
        for (int kk = 0; kk < 2; ++kk) {
            const int abyte = lj * 128 + ((64 * kk + 16 * lg) ^ SWZ(lj));
            const bf16x8 pa = *(const bf16x8*)(PlW + (abyte >> 1));
            const int ks = ch * 2 + kk;
            {
                const int cr = lj;
                const int vbyte = cr * 512 + ((64 * ks + 16 * lg) ^ SWZ(cr));
                const bf16x8 vb = *(const bf16x8*)(Vt + (vbyte >> 1));
                o0 = __builtin_amdgcn_mfma_f32_16x16x32_bf16(pa, vb, o0, 0, 0, 0);
            }
            {
                const int cr = 16 + lj;
                const int vbyte = cr * 512 + ((64 * ks + 16 * lg) ^ SWZ(cr));
                const bf16x8 vb = *(const bf16x8*)(Vt + (vbyte >> 1));
                o1 = __builtin_amdgcn_mfma_f32_16x16x32_bf16(pa, vb, o1, 0, 0, 0);
            }
        }
    }

    #pragma unroll
    for (int r = 0; r < 4; ++r) {
        const int qrow = q0 + lg * 4 + r;
        const size_t rowbase = ((size_t)(b2 * 256 + qrow)) * 256 + h * 32;
        {
            const float gv = bf2f(g_ws[rowbase + lj]);
            wa_ws[rowbase + lj] = f2bf(o0[r] * inv[r] * gv);
        }
        {
            const float gv = bf2f(g_ws[rowbase + 16 + lj]);
            wa_ws[rowbase + 16 + lj] = f2bf(o1[r] * inv[r] * gv);
        }
    }
}

// ---------------- Kernel 3: MFMA output projection (swapped operands) ------
// out[m][o] = sum_e WA[m][e] Wo[o][e] + bo[o]. A = Wo rows (o), B = WA rows.
__global__ __launch_bounds__(256) void out_mfma_kernel(
    const ushort* __restrict__ WA,   // bf16 [32768][256]
    const ushort* __restrict__ Wob,  // bf16 [256][256]
    const float* __restrict__ bo,    // [256]
    float* __restrict__ out)         // [32768][256]
{
    __shared__ ushort Als[128 * 32];  // Wo tile (o rows)
    __shared__ ushort Bls[128 * 32];  // WA tile (m rows)

    const int tid  = threadIdx.x;
    const int w    = tid >> 6;
    const int lane = tid & 63;
    const int lj   = lane & 15;
    const int lg   = lane >> 4;
    const int wm   = w >> 1;
    const int wn   = w & 1;
    const int m0   = blockIdx.x * 128;
    const int o0b  = blockIdx.y * 128;

    f32x4 acc[4][4];
    #pragma unroll
    for (int i = 0; i < 4; ++i)
        #pragma unroll
        for (int j = 0; j < 4; ++j) acc[i][j] = (f32x4){0.f, 0.f, 0.f, 0.f};

    const int srow = lane >> 2;
    const int scol = (((lane & 3) ^ ((lane >> 3) & 3)) << 3);
    const int xsl  = ((lg ^ ((lj >> 1) & 3)) << 3);

    for (int k0 = 0; k0 < 256; k0 += 32) {
        #pragma unroll
        for (int c = 0; c < 2; ++c) {
            const int ci = w * 2 + c;
            gload_lds16(Wob + (size_t)(o0b + ci * 16 + srow) * 256 + k0 + scol,
                        (char*)Als + ci * 1024);
            gload_lds16(WA  + (size_t)(m0 + ci * 16 + srow) * 256 + k0 + scol,
                        (char*)Bls + ci * 1024);
        }
        __syncthreads();
        bf16x8 af[4], bfr[4];
        #pragma unroll
        for (int i = 0; i < 4; ++i)
            af[i] = *(const bf16x8*)(Als + (wm * 64 + i * 16 + lj) * 32 + xsl);
        #pragma unroll
        for (int j = 0; j < 4; ++j)
            bfr[j] = *(const bf16x8*)(Bls + (wn * 64 + j * 16 + lj) * 32 + xsl);
        #pragma unroll
        for (int i = 0; i < 4; ++i)
            #pragma unroll
            for (int j = 0; j < 4; ++j)
                acc[i][j] = __builtin_amdgcn_mfma_f32_16x16x32_bf16(af[i], bfr[j], acc[i][j], 0, 0, 0);
        __syncthreads();
    }

    #pragma unroll
    for (int i = 0; i < 4; ++i) {
        const int oo = o0b + wm * 64 + i * 16 + lg * 4;
        float b4[4];
        #pragma unroll
        for (int r = 0; r < 4; ++r) b4[r] = bo[oo + r];
        #pragma unroll
        for (int j = 0; j < 4; ++j) {
            const int m = m0 + wn * 64 + j * 16 + lj;
            float4 o;
            o.x = acc[i][j][0] + b4[0];
            o.y = acc[i][j][1] + b4[1];
            o.z = acc[i][j][2] + b4[2];
            o.w = acc[i][j][3] + b4[3];
            *(float4*)(out + (size_t)m * 256 + oo) = o;
        }
    }
}

extern "C" void kernel_launch(void* const* d_in, const int* in_sizes, int n_in,
                              void* d_out, int out_size, void* d_ws, size_t ws_size,
                              hipStream_t stream) {
    const float* in_data = (const float*)d_in[0];
    const float* mask    = (const float*)d_in[1];
    const float* nb_bias = (const float*)d_in[2];
    const float* w_qkv   = (const float*)d_in[3];
    const float* w_gate  = (const float*)d_in[4];
    const float* g_bias  = (const float*)d_in[5];
    const float* w_o     = (const float*)d_in[6];
    const float* b_o     = (const float*)d_in[7];
    float* out = (float*)d_out;

    ushort* ws = (ushort*)d_ws;
    const size_t per_head = (size_t)B2 * NHEAD * NSEQ * CDIM;  // 8,388,608
    ushort* q_ws   = ws;
    ushort* k_ws   = q_ws + per_head;
    ushort* v_ws   = k_ws + per_head;
    ushort* g_ws   = v_ws + per_head;                 // [32768][256]
    ushort* wa_ws  = g_ws + (size_t)NROWS * HC;
    ushort* xb     = wa_ws + (size_t)NROWS * HC;      // [32768][256]
    ushort* wqkvgb = xb + (size_t)NROWS * DMODEL;     // [1024][256]
    ushort* wob    = wqkvgb + 1024 * 256;             // [256][256]

    convert_kernel<<<dim3(2048), 256, 0, stream>>>(
        in_data, w_qkv, w_gate, w_o, xb, wqkvgb, wob);

    qkvg_mfma_kernel<<<dim3(NROWS / 128, 8), 256, 0, stream>>>(
        xb, wqkvgb, g_bias, q_ws, k_ws, v_ws, g_ws);

    attn_mfma_kernel<<<dim3(B2 * NHEAD * 2), 512, 0, stream>>>(
        q_ws, k_ws, v_ws, g_ws, nb_bias, mask, wa_ws);

    out_mfma_kernel<<<dim3(NROWS / 128, 2), 256, 0, stream>>>(
        wa_ws, wob, b_o, out);
}

// Round 5
// 103.131 us; speedup vs baseline: 1.2281x; 1.2281x over previous
//
#include <hip/hip_runtime.h>
#include <hip/hip_bf16.h>
#include <math.h>

// Problem constants
#define B2      128
#define NSEQ    256
#define DMODEL  256
#define NHEAD   8
#define CDIM    32
#define HC      256
#define NROWS   (B2*NSEQ)    // 32768
#define SCALING 0.17677669529663687f  // 1/sqrt(32)

typedef __attribute__((ext_vector_type(8))) short bf16x8;
typedef __attribute__((ext_vector_type(4))) float f32x4;

static __device__ __forceinline__ ushort f2bf(float f) {
    __hip_bfloat16 b = __float2bfloat16(f);
    ushort r; __builtin_memcpy(&r, &b, 2); return r;
}
static __device__ __forceinline__ float bf2f(ushort u) {
    __hip_bfloat16 b; __builtin_memcpy(&b, &u, 2); return __bfloat162float(b);
}
static __device__ __forceinline__ void gload_lds16(const void* g, void* l) {
    __builtin_amdgcn_global_load_lds((const __attribute__((address_space(1))) void*)g,
                                     (__attribute__((address_space(3))) void*)l, 16, 0, 0);
}

// ---------------- Kernel 0: fp32 -> bf16 conversion ----------------
__global__ __launch_bounds__(256) void convert_kernel(
    const float* __restrict__ X, const float* __restrict__ Wqkv,
    const float* __restrict__ Wg, const float* __restrict__ Wo,
    ushort* __restrict__ xb, ushort* __restrict__ wqkvgb, ushort* __restrict__ wob)
{
    const int NX = 8388608 / 4, NQ = 196608 / 4, NG = 65536 / 4, NO = 65536 / 4;
    const int total = NX + NQ + NG + NO;
    for (int idx = blockIdx.x * 256 + threadIdx.x; idx < total; idx += gridDim.x * 256) {
        const float* src; ushort* dst; int off; float scale = 1.0f;
        if (idx < NX)                { src = X;    dst = xb;              off = idx; }
        else if (idx < NX + NQ)      { src = Wqkv; dst = wqkvgb;          off = idx - NX;
                                       if (off < 16384) scale = SCALING; }   // q rows 0..255
        else if (idx < NX + NQ + NG) { src = Wg;   dst = wqkvgb + 196608; off = idx - NX - NQ; }
        else                         { src = Wo;   dst = wob;             off = idx - NX - NQ - NG; }
        float4 v = ((const float4*)src)[off];
        union { ushort u[4]; uint2 q; } p;
        p.u[0] = f2bf(v.x * scale); p.u[1] = f2bf(v.y * scale);
        p.u[2] = f2bf(v.z * scale); p.u[3] = f2bf(v.w * scale);
        *(uint2*)(dst + (size_t)off * 4) = p.q;
    }
}

// ---------------- Kernel 1: MFMA QKV+gate projection ----------------
// D[e][m] = sum_k W[e][k] X[m][k]. A=W rows (e), B=X rows (m).
// Epilogue: acc -> swizzled LDS tile T[ml][el] -> fully coalesced stores.
__global__ __launch_bounds__(256) void qkvg_mfma_kernel(
    const ushort* __restrict__ Xb,     // bf16 [32768][256]
    const ushort* __restrict__ Wb,     // bf16 [1024][256] (q rows pre-scaled)
    const float* __restrict__ gbias,   // [256]
    ushort* __restrict__ q_ws,         // bf16 [128*8][256][32]
    ushort* __restrict__ k_ws,
    ushort* __restrict__ v_ws,
    ushort* __restrict__ g_ws)         // bf16 [32768][256]
{
    __shared__ ushort S[128 * 128];    // 32KB: staging (16KB) then transpose tile
    ushort* Als = S;                   // W tile (e rows) 8KB
    ushort* Bls = S + 4096;            // X tile (m rows) 8KB

    const int tid  = threadIdx.x;
    const int w    = tid >> 6;
    const int lane = tid & 63;
    const int lj   = lane & 15;
    const int lg   = lane >> 4;
    const int wm   = w >> 1;           // e 64-block
    const int wn   = w & 1;            // m 64-block
    const int m0   = blockIdx.x * 128;
    const int nb   = blockIdx.y;       // 0..7 over 1024 e-cols
    const int e0   = nb * 128;

    f32x4 acc[4][4];
    #pragma unroll
    for (int i = 0; i < 4; ++i)
        #pragma unroll
        for (int j = 0; j < 4; ++j) acc[i][j] = (f32x4){0.f, 0.f, 0.f, 0.f};

    // staging lane constants (pre-swizzled global k-chunk, rule #21)
    const int srow = lane >> 2;
    const int scol = (((lane & 3) ^ ((lane >> 3) & 3)) << 3);
    const int xsl  = ((lg ^ ((lj >> 1) & 3)) << 3);

    for (int k0 = 0; k0 < 256; k0 += 32) {
        #pragma unroll
        for (int c = 0; c < 2; ++c) {
            const int ci = w * 2 + c;
            gload_lds16(Wb + (size_t)(e0 + ci * 16 + srow) * 256 + k0 + scol,
                        (char*)Als + ci * 1024);
            gload_lds16(Xb + (size_t)(m0 + ci * 16 + srow) * 256 + k0 + scol,
                        (char*)Bls + ci * 1024);
        }
        __syncthreads();
        bf16x8 af[4], bfr[4];
        #pragma unroll
        for (int i = 0; i < 4; ++i)
            af[i] = *(const bf16x8*)(Als + (wm * 64 + i * 16 + lj) * 32 + xsl);
        #pragma unroll
        for (int j = 0; j < 4; ++j)
            bfr[j] = *(const bf16x8*)(Bls + (wn * 64 + j * 16 + lj) * 32 + xsl);
        #pragma unroll
        for (int i = 0; i < 4; ++i)
            #pragma unroll
            for (int j = 0; j < 4; ++j)
                acc[i][j] = __builtin_amdgcn_mfma_f32_16x16x32_bf16(af[i], bfr[j], acc[i][j], 0, 0, 0);
        __syncthreads();
    }

    // ---- epilogue stage 1: acc -> LDS tile T[ml][el], swizzled ----
    // word addr = (ml*64 + el/2) ^ (((ml>>1)&7)<<2); 2-word (uint2) writes.
    const int seg = nb >> 1;           // 0=q 1=k 2=v 3=gate
    uint* T = (uint*)S;
    #pragma unroll
    for (int i = 0; i < 4; ++i) {
        const int el0 = wm * 64 + i * 16 + lg * 4;   // 4 consecutive e-local
        const int eb  = (nb & 1) * 128 + el0;        // e within 256-segment
        #pragma unroll
        for (int j = 0; j < 4; ++j) {
            const int ml = wn * 64 + j * 16 + lj;
            union { ushort u[4]; uint2 v; } pk;
            if (seg == 3) {
                #pragma unroll
                for (int r = 0; r < 4; ++r) {
                    const float z = acc[i][j][r] + gbias[eb + r];
                    pk.u[r] = f2bf(1.f / (1.f + __expf(-z)));
                }
            } else {
                #pragma unroll
                for (int r = 0; r < 4; ++r) pk.u[r] = f2bf(acc[i][j][r]);
            }
            const int wd = (ml * 64 + (el0 >> 1)) ^ (((ml >> 1) & 7) << 2);
            *(uint2*)(T + wd) = pk.v;
        }
    }
    __syncthreads();

    // ---- epilogue stage 2: LDS -> global, fully coalesced ----
    if (seg < 3) {
        // wave w handles head-local w; per-head region is contiguous 8KB
        ushort* base = (seg == 0) ? q_ws : (seg == 1) ? k_ws : v_ws;
        const int b2 = m0 >> 8;
        const int n0 = m0 & 255;
        const int h  = (nb & 1) * 4 + w;
        ushort* gdst = base + ((size_t)(b2 * 8 + h) * 256 + n0) * 32;
        #pragma unroll
        for (int it = 0; it < 8; ++it) {
            const int ml = it * 16 + (lane >> 2);
            const int c0 = (lane & 3) * 8;
            const int el = w * 32 + c0;
            const int wd = (ml * 64 + (el >> 1)) ^ (((ml >> 1) & 7) << 2);
            const uint4 d = *(const uint4*)(T + wd);
            *(uint4*)(gdst + (size_t)it * 512 + lane * 8) = d;  // 1KB/instr dense
        }
    } else {
        // gate: g_ws[m][e], half-row (128 e) per block
        const int ml = tid >> 1;
        const int q  = tid & 1;
        ushort* gdst = g_ws + (size_t)(m0 + ml) * 256 + (nb & 1) * 128 + q * 64;
        #pragma unroll
        for (int it = 0; it < 8; ++it) {
            const int el = q * 64 + it * 8;
            const int wd = (ml * 64 + (el >> 1)) ^ (((ml >> 1) & 7) << 2);
            const uint4 d = *(const uint4*)(T + wd);
            *(uint4*)(gdst + it * 8) = d;
        }
    }
}

// ---------------- Kernel 2: MFMA attention (unchanged) ----------------
#define SWZ(c) ((((c) >> 2) & 3) << 5)

__global__ __launch_bounds__(512) void attn_mfma_kernel(
    const ushort* __restrict__ q_ws,
    const ushort* __restrict__ k_ws,
    const ushort* __restrict__ v_ws,
    const ushort* __restrict__ g_ws,
    const float* __restrict__ bias,   // [8][256][256]
    const float* __restrict__ mask,   // [128][256]
    ushort* __restrict__ wa_ws)       // bf16 [32768][256]
{
    __shared__ ushort Ks[256 * 32];
    __shared__ ushort Vt[32 * 256];
    __shared__ ushort Pl[8 * 16 * 64];

    const int tid  = threadIdx.x;
    const int bh   = blockIdx.x >> 1;
    const int half = blockIdx.x & 1;
    const int b2   = bh >> 3;
    const int h    = bh & 7;
    const int w    = tid >> 6;
    const int lane = tid & 63;
    const int lj   = lane & 15;
    const int lg   = lane >> 4;

    {
        const uint4* gk = (const uint4*)(k_ws + (size_t)bh * 8192);
        uint4* sk = (uint4*)Ks;
        sk[tid]       = gk[tid];
        sk[tid + 512] = gk[tid + 512];
    }
    {
        const int cq = tid & 3;
        #pragma unroll
        for (int it = 0; it < 2; ++it) {
            const int n = it * 128 + (tid >> 2);
            uint4 v = *(const uint4*)(v_ws + (size_t)bh * 8192 + n * 32 + cq * 8);
            const ushort* pv = (const ushort*)&v;
            #pragma unroll
            for (int e = 0; e < 8; ++e) {
                const int c = cq * 8 + e;
                const int byte = c * 512 + ((2 * n) ^ SWZ(c));
                Vt[byte >> 1] = pv[e];
            }
        }
    }

    const int q0 = half * 128 + w * 16;
    const bf16x8 qf = *(const bf16x8*)(q_ws + (size_t)bh * 8192 + (size_t)(q0 + lj) * 32 + lg * 8);

    __syncthreads();

    f32x4 acc[16];
    const float* bbase = bias + (size_t)h * 256 * 256;
    const float* mrow  = mask + (size_t)b2 * 256;
    #pragma unroll
    for (int t = 0; t < 16; ++t) {
        const int col = t * 16 + lj;
        const float mterm = (mrow[col] - 1.0f) * 1e9f;
        #pragma unroll
        for (int r = 0; r < 4; ++r) {
            const int qrow = q0 + lg * 4 + r;
            acc[t][r] = bbase[(size_t)qrow * 256 + col] + mterm;
        }
    }

    #pragma unroll
    for (int t = 0; t < 16; ++t) {
        const bf16x8 kf = *(const bf16x8*)(Ks + (t * 16 + lj) * 32 + lg * 8);
        acc[t] = __builtin_amdgcn_mfma_f32_16x16x32_bf16(qf, kf, acc[t], 0, 0, 0);
    }

    float inv[4];
    #pragma unroll
    for (int r = 0; r < 4; ++r) {
        float m = acc[0][r];
        #pragma unroll
        for (int t = 1; t < 16; ++t) m = fmaxf(m, acc[t][r]);
        m = fmaxf(m, __shfl_xor(m, 1));
        m = fmaxf(m, __shfl_xor(m, 2));
        m = fmaxf(m, __shfl_xor(m, 4));
        m = fmaxf(m, __shfl_xor(m, 8));
        float s = 0.f;
        #pragma unroll
        for (int t = 0; t < 16; ++t) {
            float e = __expf(acc[t][r] - m);
            acc[t][r] = e;
            s += e;
        }
        s += __shfl_xor(s, 1);
        s += __shfl_xor(s, 2);
        s += __shfl_xor(s, 4);
        s += __shfl_xor(s, 8);
        inv[r] = 1.0f / s;
    }

    ushort* PlW = Pl + w * 1024;
    f32x4 o0 = {0.f, 0.f, 0.f, 0.f};
    f32x4 o1 = {0.f, 0.f, 0.f, 0.f};
    #pragma unroll
    for (int ch = 0; ch < 4; ++ch) {
        #pragma unroll
        for (int tt = 0; tt < 4; ++tt) {
            const int t = ch * 4 + tt;
            #pragma unroll
            for (int r = 0; r < 4; ++r) {
                const int row  = lg * 4 + r;
                const int byte = row * 128 + ((32 * tt + 2 * lj) ^ (lg << 5));
                PlW[byte >> 1] = f2bf(acc[t][r]);
            }
        }
        #pragma unroll
        for (int kk = 0; kk < 2; ++kk) {
            const int abyte = lj * 128 + ((64 * kk + 16 * lg) ^ SWZ(lj));
            const bf16x8 pa = *(const bf16x8*)(PlW + (abyte >> 1));
            const int ks = ch * 2 + kk;
            {
                const int cr = lj;
                const int vbyte = cr * 512 + ((64 * ks + 16 * lg) ^ SWZ(cr));
                const bf16x8 vb = *(const bf16x8*)(Vt + (vbyte >> 1));
                o0 = __builtin_amdgcn_mfma_f32_16x16x32_bf16(pa, vb, o0, 0, 0, 0);
            }
            {
                const int cr = 16 + lj;
                const int vbyte = cr * 512 + ((64 * ks + 16 * lg) ^ SWZ(cr));
                const bf16x8 vb = *(const bf16x8*)(Vt + (vbyte >> 1));
                o1 = __builtin_amdgcn_mfma_f32_16x16x32_bf16(pa, vb, o1, 0, 0, 0);
            }
        }
    }

    #pragma unroll
    for (int r = 0; r < 4; ++r) {
        const int qrow = q0 + lg * 4 + r;
        const size_t rowbase = ((size_t)(b2 * 256 + qrow)) * 256 + h * 32;
        {
            const float gv = bf2f(g_ws[rowbase + lj]);
            wa_ws[rowbase + lj] = f2bf(o0[r] * inv[r] * gv);
        }
        {
            const float gv = bf2f(g_ws[rowbase + 16 + lj]);
            wa_ws[rowbase + 16 + lj] = f2bf(o1[r] * inv[r] * gv);
        }
    }
}

// ---------------- Kernel 3: MFMA output projection (non-swapped) ------
// out[m][o] = sum_e WA[m][e] Wo[o][e] + bo[o]. A=WA rows (m), B=Wo rows (o).
// D col = o -> 16 lanes cover 64B full lines.
__global__ __launch_bounds__(256) void out_mfma_kernel(
    const ushort* __restrict__ WA,   // bf16 [32768][256]
    const ushort* __restrict__ Wob,  // bf16 [256][256]
    const float* __restrict__ bo,    // [256]
    float* __restrict__ out)         // [32768][256]
{
    __shared__ ushort Als[128 * 32];  // WA tile (m rows)
    __shared__ ushort Bls[128 * 32];  // Wo tile (o rows)

    const int tid  = threadIdx.x;
    const int w    = tid >> 6;
    const int lane = tid & 63;
    const int lj   = lane & 15;
    const int lg   = lane >> 4;
    const int wm   = w >> 1;
    const int wn   = w & 1;
    const int m0   = blockIdx.x * 128;
    const int o0b  = blockIdx.y * 128;

    f32x4 acc[4][4];
    #pragma unroll
    for (int i = 0; i < 4; ++i)
        #pragma unroll
        for (int j = 0; j < 4; ++j) acc[i][j] = (f32x4){0.f, 0.f, 0.f, 0.f};

    const int srow = lane >> 2;
    const int scol = (((lane & 3) ^ ((lane >> 3) & 3)) << 3);
    const int xsl  = ((lg ^ ((lj >> 1) & 3)) << 3);

    for (int k0 = 0; k0 < 256; k0 += 32) {
        #pragma unroll
        for (int c = 0; c < 2; ++c) {
            const int ci = w * 2 + c;
            gload_lds16(WA  + (size_t)(m0 + ci * 16 + srow) * 256 + k0 + scol,
                        (char*)Als + ci * 1024);
            gload_lds16(Wob + (size_t)(o0b + ci * 16 + srow) * 256 + k0 + scol,
                        (char*)Bls + ci * 1024);
        }
        __syncthreads();
        bf16x8 af[4], bfr[4];
        #pragma unroll
        for (int i = 0; i < 4; ++i)
            af[i] = *(const bf16x8*)(Als + (wm * 64 + i * 16 + lj) * 32 + xsl);
        #pragma unroll
        for (int j = 0; j < 4; ++j)
            bfr[j] = *(const bf16x8*)(Bls + (wn * 64 + j * 16 + lj) * 32 + xsl);
        #pragma unroll
        for (int i = 0; i < 4; ++i)
            #pragma unroll
            for (int j = 0; j < 4; ++j)
                acc[i][j] = __builtin_amdgcn_mfma_f32_16x16x32_bf16(af[i], bfr[j], acc[i][j], 0, 0, 0);
        __syncthreads();
    }

    // D row (reg) = m, D col (lane lj) = o -> full-line 4B stores
    #pragma unroll
    for (int i = 0; i < 4; ++i) {
        #pragma unroll
        for (int r = 0; r < 4; ++r) {
            const int m = m0 + wm * 64 + i * 16 + lg * 4 + r;
            #pragma unroll
            for (int j = 0; j < 4; ++j) {
                const int o = o0b + wn * 64 + j * 16 + lj;
                out[(size_t)m * 256 + o] = acc[i][j][r] + bo[o];
            }
        }
    }
}

extern "C" void kernel_launch(void* const* d_in, const int* in_sizes, int n_in,
                              void* d_out, int out_size, void* d_ws, size_t ws_size,
                              hipStream_t stream) {
    const float* in_data = (const float*)d_in[0];
    const float* mask    = (const float*)d_in[1];
    const float* nb_bias = (const float*)d_in[2];
    const float* w_qkv   = (const float*)d_in[3];
    const float* w_gate  = (const float*)d_in[4];
    const float* g_bias  = (const float*)d_in[5];
    const float* w_o     = (const float*)d_in[6];
    const float* b_o     = (const float*)d_in[7];
    float* out = (float*)d_out;

    ushort* ws = (ushort*)d_ws;
    const size_t per_head = (size_t)B2 * NHEAD * NSEQ * CDIM;  // 8,388,608
    ushort* q_ws   = ws;
    ushort* k_ws   = q_ws + per_head;
    ushort* v_ws   = k_ws + per_head;
    ushort* g_ws   = v_ws + per_head;                 // [32768][256]
    ushort* wa_ws  = g_ws + (size_t)NROWS * HC;
    ushort* xb     = wa_ws + (size_t)NROWS * HC;      // [32768][256]
    ushort* wqkvgb = xb + (size_t)NROWS * DMODEL;     // [1024][256]
    ushort* wob    = wqkvgb + 1024 * 256;             // [256][256]

    convert_kernel<<<dim3(2048), 256, 0, stream>>>(
        in_data, w_qkv, w_gate, w_o, xb, wqkvgb, wob);

    qkvg_mfma_kernel<<<dim3(NROWS / 128, 8), 256, 0, stream>>>(
        xb, wqkvgb, g_bias, q_ws, k_ws, v_ws, g_ws);

    attn_mfma_kernel<<<dim3(B2 * NHEAD * 2), 512, 0, stream>>>(
        q_ws, k_ws, v_ws, g_ws, nb_bias, mask, wa_ws);

    out_mfma_kernel<<<dim3(NROWS / 128, 2), 256, 0, stream>>>(
        wa_ws, wob, b_o, out);
}

// Round 6
// 101.283 us; speedup vs baseline: 1.2505x; 1.0182x over previous
//
#include <hip/hip_runtime.h>
#include <hip/hip_bf16.h>
#include <math.h>

// Problem constants
#define B2      128
#define NSEQ    256
#define DMODEL  256
#define NHEAD   8
#define CDIM    32
#define HC      256
#define NROWS   (B2*NSEQ)    // 32768
#define SCALING 0.17677669529663687f  // 1/sqrt(32)

typedef __attribute__((ext_vector_type(8))) short bf16x8;
typedef __attribute__((ext_vector_type(4))) float f32x4;

static __device__ __forceinline__ ushort f2bf(float f) {
    __hip_bfloat16 b = __float2bfloat16(f);
    ushort r; __builtin_memcpy(&r, &b, 2); return r;
}
static __device__ __forceinline__ float bf2f(ushort u) {
    __hip_bfloat16 b; __builtin_memcpy(&b, &u, 2); return __bfloat162float(b);
}
static __device__ __forceinline__ void gload_lds16(const void* g, void* l) {
    __builtin_amdgcn_global_load_lds((const __attribute__((address_space(1))) void*)g,
                                     (__attribute__((address_space(3))) void*)l, 16, 0, 0);
}

// ---------------- Kernel 0: fp32 -> bf16 conversion ----------------
__global__ __launch_bounds__(256) void convert_kernel(
    const float* __restrict__ X, const float* __restrict__ Wqkv,
    const float* __restrict__ Wg, const float* __restrict__ Wo,
    ushort* __restrict__ xb, ushort* __restrict__ wqkvgb, ushort* __restrict__ wob)
{
    const int NX = 8388608 / 4, NQ = 196608 / 4, NG = 65536 / 4, NO = 65536 / 4;
    const int total = NX + NQ + NG + NO;
    for (int idx = blockIdx.x * 256 + threadIdx.x; idx < total; idx += gridDim.x * 256) {
        const float* src; ushort* dst; int off; float scale = 1.0f;
        if (idx < NX)                { src = X;    dst = xb;              off = idx; }
        else if (idx < NX + NQ)      { src = Wqkv; dst = wqkvgb;          off = idx - NX;
                                       if (off < 16384) scale = SCALING; }   // q rows 0..255
        else if (idx < NX + NQ + NG) { src = Wg;   dst = wqkvgb + 196608; off = idx - NX - NQ; }
        else                         { src = Wo;   dst = wob;             off = idx - NX - NQ - NG; }
        float4 v = ((const float4*)src)[off];
        union { ushort u[4]; uint2 q; } p;
        p.u[0] = f2bf(v.x * scale); p.u[1] = f2bf(v.y * scale);
        p.u[2] = f2bf(v.z * scale); p.u[3] = f2bf(v.w * scale);
        *(uint2*)(dst + (size_t)off * 4) = p.q;
    }
}

// ---------------- Kernel 1: MFMA QKV+gate projection (2-phase pipeline) ----
// D[e][m] = sum_k W[e][k] X[m][k]. A=W rows (e), B=X rows (m).
// Double-buffered global_load_lds staging; single raw barrier per K-step.
// Epilogue: acc -> swizzled LDS tile (aliases staging) -> coalesced stores.
__global__ __launch_bounds__(256) void qkvg_mfma_kernel(
    const ushort* __restrict__ Xb,     // bf16 [32768][256]
    const ushort* __restrict__ Wb,     // bf16 [1024][256] (q rows pre-scaled)
    const float* __restrict__ gbias,   // [256]
    ushort* __restrict__ q_ws,         // bf16 [128*8][256][32]
    ushort* __restrict__ k_ws,
    ushort* __restrict__ v_ws,
    ushort* __restrict__ g_ws)         // bf16 [32768][256]
{
    __shared__ ushort S[128 * 128];    // 32KB: dbuf staging, then transpose tile
    ushort* const Abuf[2] = { S,        S + 8192 };
    ushort* const Bbuf[2] = { S + 4096, S + 12288 };

    const int tid  = threadIdx.x;
    const int w    = tid >> 6;
    const int lane = tid & 63;
    const int lj   = lane & 15;
    const int lg   = lane >> 4;
    const int wm   = w >> 1;           // e 64-block
    const int wn   = w & 1;            // m 64-block
    const int m0   = blockIdx.x * 128;
    const int nb   = blockIdx.y;       // 0..7 over 1024 e-cols
    const int e0   = nb * 128;

    f32x4 acc[4][4];
    #pragma unroll
    for (int i = 0; i < 4; ++i)
        #pragma unroll
        for (int j = 0; j < 4; ++j) acc[i][j] = (f32x4){0.f, 0.f, 0.f, 0.f};

    // staging lane constants (pre-swizzled global k-chunk, rule #21)
    const int srow = lane >> 2;
    const int scol = (((lane & 3) ^ ((lane >> 3) & 3)) << 3);
    const int xsl  = ((lg ^ ((lj >> 1) & 3)) << 3);

    #define QSTAGE(Adst, Bdst, kk) do {                                          \
        _Pragma("unroll")                                                        \
        for (int c = 0; c < 2; ++c) {                                            \
            const int ci = w * 2 + c;                                            \
            gload_lds16(Wb + (size_t)(e0 + ci * 16 + srow) * 256 + (kk) + scol,  \
                        (char*)(Adst) + ci * 1024);                              \
            gload_lds16(Xb + (size_t)(m0 + ci * 16 + srow) * 256 + (kk) + scol,  \
                        (char*)(Bdst) + ci * 1024);                              \
        } } while (0)

    // prologue
    QSTAGE(Abuf[0], Bbuf[0], 0);
    asm volatile("s_waitcnt vmcnt(0)" ::: "memory");
    __builtin_amdgcn_s_barrier();

    #pragma unroll
    for (int t = 0; t < 8; ++t) {
        ushort* Ac = Abuf[t & 1];
        ushort* Bc = Bbuf[t & 1];
        if (t < 7) QSTAGE(Abuf[(t + 1) & 1], Bbuf[(t + 1) & 1], (t + 1) * 32);
        bf16x8 af[4], bfr[4];
        #pragma unroll
        for (int i = 0; i < 4; ++i)
            af[i] = *(const bf16x8*)(Ac + (wm * 64 + i * 16 + lj) * 32 + xsl);
        #pragma unroll
        for (int j = 0; j < 4; ++j)
            bfr[j] = *(const bf16x8*)(Bc + (wn * 64 + j * 16 + lj) * 32 + xsl);
        #pragma unroll
        for (int i = 0; i < 4; ++i)
            #pragma unroll
            for (int j = 0; j < 4; ++j)
                acc[i][j] = __builtin_amdgcn_mfma_f32_16x16x32_bf16(af[i], bfr[j], acc[i][j], 0, 0, 0);
        asm volatile("s_waitcnt vmcnt(0)" ::: "memory");
        __builtin_amdgcn_s_barrier();
    }
    #undef QSTAGE

    // ---- epilogue stage 1: acc -> LDS tile T[ml][el], swizzled ----
    const int seg = nb >> 1;           // 0=q 1=k 2=v 3=gate
    uint* T = (uint*)S;
    #pragma unroll
    for (int i = 0; i < 4; ++i) {
        const int el0 = wm * 64 + i * 16 + lg * 4;   // 4 consecutive e-local
        const int eb  = (nb & 1) * 128 + el0;        // e within 256-segment
        #pragma unroll
        for (int j = 0; j < 4; ++j) {
            const int ml = wn * 64 + j * 16 + lj;
            union { ushort u[4]; uint2 v; } pk;
            if (seg == 3) {
                #pragma unroll
                for (int r = 0; r < 4; ++r) {
                    const float z = acc[i][j][r] + gbias[eb + r];
                    pk.u[r] = f2bf(1.f / (1.f + __expf(-z)));
                }
            } else {
                #pragma unroll
                for (int r = 0; r < 4; ++r) pk.u[r] = f2bf(acc[i][j][r]);
            }
            const int wd = (ml * 64 + (el0 >> 1)) ^ (((ml >> 1) & 7) << 2);
            *(uint2*)(T + wd) = pk.v;
        }
    }
    __syncthreads();

    // ---- epilogue stage 2: LDS -> global, fully coalesced ----
    if (seg < 3) {
        ushort* base = (seg == 0) ? q_ws : (seg == 1) ? k_ws : v_ws;
        const int b2 = m0 >> 8;
        const int n0 = m0 & 255;
        const int h  = (nb & 1) * 4 + w;
        ushort* gdst = base + ((size_t)(b2 * 8 + h) * 256 + n0) * 32;
        #pragma unroll
        for (int it = 0; it < 8; ++it) {
            const int ml = it * 16 + (lane >> 2);
            const int c0 = (lane & 3) * 8;
            const int el = w * 32 + c0;
            const int wd = (ml * 64 + (el >> 1)) ^ (((ml >> 1) & 7) << 2);
            const uint4 d = *(const uint4*)(T + wd);
            *(uint4*)(gdst + (size_t)it * 512 + lane * 8) = d;
        }
    } else {
        const int ml = tid >> 1;
        const int q  = tid & 1;
        ushort* gdst = g_ws + (size_t)(m0 + ml) * 256 + (nb & 1) * 128 + q * 64;
        #pragma unroll
        for (int it = 0; it < 8; ++it) {
            const int el = q * 64 + it * 8;
            const int wd = (ml * 64 + (el >> 1)) ^ (((ml >> 1) & 7) << 2);
            const uint4 d = *(const uint4*)(T + wd);
            *(uint4*)(gdst + it * 8) = d;
        }
    }
}

// ---------------- Kernel 2: MFMA attention ----------------
#define SWZ(c) ((((c) >> 2) & 3) << 5)

__global__ __launch_bounds__(512) void attn_mfma_kernel(
    const ushort* __restrict__ q_ws,
    const ushort* __restrict__ k_ws,
    const ushort* __restrict__ v_ws,
    const ushort* __restrict__ g_ws,
    const float* __restrict__ bias,   // [8][256][256]
    const float* __restrict__ mask,   // [128][256]
    ushort* __restrict__ wa_ws)       // bf16 [32768][256]
{
    __shared__ ushort Ks[256 * 32];
    __shared__ ushort Vt[32 * 256];
    __shared__ ushort Pl[8 * 16 * 64];

    const int tid  = threadIdx.x;
    const int bh   = blockIdx.x >> 1;
    const int half = blockIdx.x & 1;
    const int b2   = bh >> 3;
    const int h    = bh & 7;
    const int w    = tid >> 6;
    const int lane = tid & 63;
    const int lj   = lane & 15;
    const int lg   = lane >> 4;

    // stage K via direct global->LDS (linear; lane offset implicit)
    {
        const char* gk = (const char*)(k_ws + (size_t)bh * 8192);
        gload_lds16(gk + tid * 16,        (char*)Ks + w * 1024);
        gload_lds16(gk + 8192 + tid * 16, (char*)Ks + 8192 + w * 1024);
    }
    // stage V transposed (register path, swizzled scatter)
    {
        const int cq = tid & 3;
        #pragma unroll
        for (int it = 0; it < 2; ++it) {
            const int n = it * 128 + (tid >> 2);
            uint4 v = *(const uint4*)(v_ws + (size_t)bh * 8192 + n * 32 + cq * 8);
            const ushort* pv = (const ushort*)&v;
            #pragma unroll
            for (int e = 0; e < 8; ++e) {
                const int c = cq * 8 + e;
                const int byte = c * 512 + ((2 * n) ^ SWZ(c));
                Vt[byte >> 1] = pv[e];
            }
        }
    }

    const int q0 = half * 128 + w * 16;
    const bf16x8 qf = *(const bf16x8*)(q_ws + (size_t)bh * 8192 + (size_t)(q0 + lj) * 32 + lg * 8);

    // accumulator init: bias + mask, issued BEFORE the barrier to overlap
    f32x4 acc[16];
    const float* bbase = bias + (size_t)h * 256 * 256;
    const float* mrow  = mask + (size_t)b2 * 256;
    #pragma unroll
    for (int t = 0; t < 16; ++t) {
        const int col = t * 16 + lj;
        const float mterm = (mrow[col] - 1.0f) * 1e9f;
        #pragma unroll
        for (int r = 0; r < 4; ++r) {
            const int qrow = q0 + lg * 4 + r;
            acc[t][r] = bbase[(size_t)qrow * 256 + col] + mterm;
        }
    }

    __syncthreads();   // drains vmcnt (gload_lds) + lgkmcnt per HIP semantics

    #pragma unroll
    for (int t = 0; t < 16; ++t) {
        const bf16x8 kf = *(const bf16x8*)(Ks + (t * 16 + lj) * 32 + lg * 8);
        acc[t] = __builtin_amdgcn_mfma_f32_16x16x32_bf16(qf, kf, acc[t], 0, 0, 0);
    }

    float inv[4];
    #pragma unroll
    for (int r = 0; r < 4; ++r) {
        float m = acc[0][r];
        #pragma unroll
        for (int t = 1; t < 16; ++t) m = fmaxf(m, acc[t][r]);
        m = fmaxf(m, __shfl_xor(m, 1));
        m = fmaxf(m, __shfl_xor(m, 2));
        m = fmaxf(m, __shfl_xor(m, 4));
        m = fmaxf(m, __shfl_xor(m, 8));
        float s = 0.f;
        #pragma unroll
        for (int t = 0; t < 16; ++t) {
            float e = __expf(acc[t][r] - m);
            acc[t][r] = e;
            s += e;
        }
        s += __shfl_xor(s, 1);
        s += __shfl_xor(s, 2);
        s += __shfl_xor(s, 4);
        s += __shfl_xor(s, 8);
        inv[r] = 1.0f / s;
    }

    ushort* PlW = Pl + w * 1024;
    f32x4 o0 = {0.f, 0.f, 0.f, 0.f};
    f32x4 o1 = {0.f, 0.f, 0.f, 0.f};
    #pragma unroll
    for (int ch = 0; ch < 4; ++ch) {
        #pragma unroll
        for (int tt = 0; tt < 4; ++tt) {
            const int t = ch * 4 + tt;
            #pragma unroll
            for (int r = 0; r < 4; ++r) {
                const int row  = lg * 4 + r;
                const int byte = row * 128 + ((32 * tt + 2 * lj) ^ (lg << 5));
                PlW[byte >> 1] = f2bf(acc[t][r]);
            }
        }
        #pragma unroll
        for (int kk = 0; kk < 2; ++kk) {
            const int abyte = lj * 128 + ((64 * kk + 16 * lg) ^ SWZ(lj));
            const bf16x8 pa = *(const bf16x8*)(PlW + (abyte >> 1));
            const int ks = ch * 2 + kk;
            {
                const int cr = lj;
                const int vbyte = cr * 512 + ((64 * ks + 16 * lg) ^ SWZ(cr));
                const bf16x8 vb = *(const bf16x8*)(Vt + (vbyte >> 1));
                o0 = __builtin_amdgcn_mfma_f32_16x16x32_bf16(pa, vb, o0, 0, 0, 0);
            }
            {
                const int cr = 16 + lj;
                const int vbyte = cr * 512 + ((64 * ks + 16 * lg) ^ SWZ(cr));
                const bf16x8 vb = *(const bf16x8*)(Vt + (vbyte >> 1));
                o1 = __builtin_amdgcn_mfma_f32_16x16x32_bf16(pa, vb, o1, 0, 0, 0);
            }
        }
    }

    #pragma unroll
    for (int r = 0; r < 4; ++r) {
        const int qrow = q0 + lg * 4 + r;
        const size_t rowbase = ((size_t)(b2 * 256 + qrow)) * 256 + h * 32;
        {
            const float gv = bf2f(g_ws[rowbase + lj]);
            wa_ws[rowbase + lj] = f2bf(o0[r] * inv[r] * gv);
        }
        {
            const float gv = bf2f(g_ws[rowbase + 16 + lj]);
            wa_ws[rowbase + 16 + lj] = f2bf(o1[r] * inv[r] * gv);
        }
    }
}

// ---------------- Kernel 3: MFMA output projection (2-phase pipeline) ------
// out[m][o] = sum_e WA[m][e] Wo[o][e] + bo[o]. A=WA rows (m), B=Wo rows (o).
__global__ __launch_bounds__(256) void out_mfma_kernel(
    const ushort* __restrict__ WA,   // bf16 [32768][256]
    const ushort* __restrict__ Wob,  // bf16 [256][256]
    const float* __restrict__ bo,    // [256]
    float* __restrict__ out)         // [32768][256]
{
    __shared__ ushort S[128 * 128];  // 32KB double-buffer staging
    ushort* const Abuf[2] = { S,        S + 8192 };
    ushort* const Bbuf[2] = { S + 4096, S + 12288 };

    const int tid  = threadIdx.x;
    const int w    = tid >> 6;
    const int lane = tid & 63;
    const int lj   = lane & 15;
    const int lg   = lane >> 4;
    const int wm   = w >> 1;
    const int wn   = w & 1;
    const int m0   = blockIdx.x * 128;
    const int o0b  = blockIdx.y * 128;

    f32x4 acc[4][4];
    #pragma unroll
    for (int i = 0; i < 4; ++i)
        #pragma unroll
        for (int j = 0; j < 4; ++j) acc[i][j] = (f32x4){0.f, 0.f, 0.f, 0.f};

    const int srow = lane >> 2;
    const int scol = (((lane & 3) ^ ((lane >> 3) & 3)) << 3);
    const int xsl  = ((lg ^ ((lj >> 1) & 3)) << 3);

    #define OSTAGE(Adst, Bdst, kk) do {                                          \
        _Pragma("unroll")                                                        \
        for (int c = 0; c < 2; ++c) {                                            \
            const int ci = w * 2 + c;                                            \
            gload_lds16(WA  + (size_t)(m0 + ci * 16 + srow) * 256 + (kk) + scol, \
                        (char*)(Adst) + ci * 1024);                              \
            gload_lds16(Wob + (size_t)(o0b + ci * 16 + srow) * 256 + (kk) + scol,\
                        (char*)(Bdst) + ci * 1024);                              \
        } } while (0)

    OSTAGE(Abuf[0], Bbuf[0], 0);
    asm volatile("s_waitcnt vmcnt(0)" ::: "memory");
    __builtin_amdgcn_s_barrier();

    #pragma unroll
    for (int t = 0; t < 8; ++t) {
        ushort* Ac = Abuf[t & 1];
        ushort* Bc = Bbuf[t & 1];
        if (t < 7) OSTAGE(Abuf[(t + 1) & 1], Bbuf[(t + 1) & 1], (t + 1) * 32);
        bf16x8 af[4], bfr[4];
        #pragma unroll
        for (int i = 0; i < 4; ++i)
            af[i] = *(const bf16x8*)(Ac + (wm * 64 + i * 16 + lj) * 32 + xsl);
        #pragma unroll
        for (int j = 0; j < 4; ++j)
            bfr[j] = *(const bf16x8*)(Bc + (wn * 64 + j * 16 + lj) * 32 + xsl);
        #pragma unroll
        for (int i = 0; i < 4; ++i)
            #pragma unroll
            for (int j = 0; j < 4; ++j)
                acc[i][j] = __builtin_amdgcn_mfma_f32_16x16x32_bf16(af[i], bfr[j], acc[i][j], 0, 0, 0);
        asm volatile("s_waitcnt vmcnt(0)" ::: "memory");
        __builtin_amdgcn_s_barrier();
    }
    #undef OSTAGE

    // D row (reg) = m, D col (lane lj) = o
    #pragma unroll
    for (int i = 0; i < 4; ++i) {
        #pragma unroll
        for (int r = 0; r < 4; ++r) {
            const int m = m0 + wm * 64 + i * 16 + lg * 4 + r;
            #pragma unroll
            for (int j = 0; j < 4; ++j) {
                const int o = o0b + wn * 64 + j * 16 + lj;
                out[(size_t)m * 256 + o] = acc[i][j][r] + bo[o];
            }
        }
    }
}

extern "C" void kernel_launch(void* const* d_in, const int* in_sizes, int n_in,
                              void* d_out, int out_size, void* d_ws, size_t ws_size,
                              hipStream_t stream) {
    const float* in_data = (const float*)d_in[0];
    const float* mask    = (const float*)d_in[1];
    const float* nb_bias = (const float*)d_in[2];
    const float* w_qkv   = (const float*)d_in[3];
    const float* w_gate  = (const float*)d_in[4];
    const float* g_bias  = (const float*)d_in[5];
    const float* w_o     = (const float*)d_in[6];
    const float* b_o     = (const float*)d_in[7];
    float* out = (float*)d_out;

    ushort* ws = (ushort*)d_ws;
    const size_t per_head = (size_t)B2 * NHEAD * NSEQ * CDIM;  // 8,388,608
    ushort* q_ws   = ws;
    ushort* k_ws   = q_ws + per_head;
    ushort* v_ws   = k_ws + per_head;
    ushort* g_ws   = v_ws + per_head;                 // [32768][256]
    ushort* wa_ws  = g_ws + (size_t)NROWS * HC;
    ushort* xb     = wa_ws + (size_t)NROWS * HC;      // [32768][256]
    ushort* wqkvgb = xb + (size_t)NROWS * DMODEL;     // [1024][256]
    ushort* wob    = wqkvgb + 1024 * 256;             // [256][256]

    convert_kernel<<<dim3(2048), 256, 0, stream>>>(
        in_data, w_qkv, w_gate, w_o, xb, wqkvgb, wob);

    qkvg_mfma_kernel<<<dim3(NROWS / 128, 8), 256, 0, stream>>>(
        xb, wqkvgb, g_bias, q_ws, k_ws, v_ws, g_ws);

    attn_mfma_kernel<<<dim3(B2 * NHEAD * 2), 512, 0, stream>>>(
        q_ws, k_ws, v_ws, g_ws, nb_bias, mask, wa_ws);

    out_mfma_kernel<<<dim3(NROWS / 128, 2), 256, 0, stream>>>(
        wa_ws, wob, b_o, out);
}

// Round 7
// 99.396 us; speedup vs baseline: 1.2742x; 1.0190x over previous
//
#include <hip/hip_runtime.h>
#include <hip/hip_bf16.h>
#include <math.h>

// Problem constants
#define B2      128
#define NSEQ    256
#define DMODEL  256
#define NHEAD   8
#define CDIM    32
#define HC      256
#define NROWS   (B2*NSEQ)    // 32768
#define SCALING 0.17677669529663687f  // 1/sqrt(32)

typedef __attribute__((ext_vector_type(8))) short bf16x8;
typedef __attribute__((ext_vector_type(4))) float f32x4;

static __device__ __forceinline__ ushort f2bf(float f) {
    __hip_bfloat16 b = __float2bfloat16(f);
    ushort r; __builtin_memcpy(&r, &b, 2); return r;
}
static __device__ __forceinline__ float bf2f(ushort u) {
    __hip_bfloat16 b; __builtin_memcpy(&b, &u, 2); return __bfloat162float(b);
}
static __device__ __forceinline__ void gload_lds16(const void* g, void* l) {
    __builtin_amdgcn_global_load_lds((const __attribute__((address_space(1))) void*)g,
                                     (__attribute__((address_space(3))) void*)l, 16, 0, 0);
}

// ---------------- Kernel 0: fp32 -> bf16 conversion ----------------
__global__ __launch_bounds__(256) void convert_kernel(
    const float* __restrict__ X, const float* __restrict__ Wqkv,
    const float* __restrict__ Wg, const float* __restrict__ Wo,
    ushort* __restrict__ xb, ushort* __restrict__ wqkvgb, ushort* __restrict__ wob)
{
    const int NX = 8388608 / 4, NQ = 196608 / 4, NG = 65536 / 4, NO = 65536 / 4;
    const int total = NX + NQ + NG + NO;
    for (int idx = blockIdx.x * 256 + threadIdx.x; idx < total; idx += gridDim.x * 256) {
        const float* src; ushort* dst; int off; float scale = 1.0f;
        if (idx < NX)                { src = X;    dst = xb;              off = idx; }
        else if (idx < NX + NQ)      { src = Wqkv; dst = wqkvgb;          off = idx - NX;
                                       if (off < 16384) scale = SCALING; }   // q rows 0..255
        else if (idx < NX + NQ + NG) { src = Wg;   dst = wqkvgb + 196608; off = idx - NX - NQ; }
        else                         { src = Wo;   dst = wob;             off = idx - NX - NQ - NG; }
        float4 v = ((const float4*)src)[off];
        union { ushort u[4]; uint2 q; } p;
        p.u[0] = f2bf(v.x * scale); p.u[1] = f2bf(v.y * scale);
        p.u[2] = f2bf(v.z * scale); p.u[3] = f2bf(v.w * scale);
        *(uint2*)(dst + (size_t)off * 4) = p.q;
    }
}

// ---------------- Kernel 1: MFMA QKV+gate projection, seg-tile ----------------
// Tile: 64 m-rows x 256 e-cols (one whole segment: q|k|v|gate).
// W-segment streams from L2 (all W = 0.5MB, L2-hot); X read once per seg.
// A=W(e rows), B=X(m rows); D row = e. Epilogue: swizzled LDS transpose ->
// coalesced per-head stores.
__global__ __launch_bounds__(256) void qkvg_mfma_kernel(
    const ushort* __restrict__ Xb,     // bf16 [32768][256]
    const ushort* __restrict__ Wb,     // bf16 [1024][256] (q rows pre-scaled)
    const float* __restrict__ gbias,   // [256]
    ushort* __restrict__ q_ws,         // bf16 [128*8][256][32]
    ushort* __restrict__ k_ws,
    ushort* __restrict__ v_ws,
    ushort* __restrict__ g_ws)         // bf16 [32768][256]
{
    __shared__ ushort S[20480];        // 40KB: Wbuf0(8192) Xbuf0(2048) Wbuf1(8192) Xbuf1(2048)
    ushort* const Wbuf[2] = { S,        S + 10240 };
    ushort* const Xbuf[2] = { S + 8192, S + 18432 };

    const int tid  = threadIdx.x;
    const int w    = tid >> 6;         // wave: e-quadrant w*64
    const int lane = tid & 63;
    const int lj   = lane & 15;
    const int lg   = lane >> 4;
    const int m0   = blockIdx.x * 64;
    const int seg  = blockIdx.y;       // 0=q 1=k 2=v 3=gate
    const int e0g  = seg * 256;        // W row base

    f32x4 acc[4][4];
    #pragma unroll
    for (int i = 0; i < 4; ++i)
        #pragma unroll
        for (int j = 0; j < 4; ++j) acc[i][j] = (f32x4){0.f, 0.f, 0.f, 0.f};

    const int srow = lane >> 2;
    const int scol = (((lane & 3) ^ ((lane >> 3) & 3)) << 3);
    const int xsl  = ((lg ^ ((lj >> 1) & 3)) << 3);

    #define QSTAGE(Wdst, Xdst, kk) do {                                          \
        _Pragma("unroll")                                                        \
        for (int c = 0; c < 4; ++c) {                                            \
            const int ci = w * 4 + c;                                            \
            gload_lds16(Wb + (size_t)(e0g + ci * 16 + srow) * 256 + (kk) + scol, \
                        (char*)(Wdst) + ci * 1024);                              \
        }                                                                        \
        gload_lds16(Xb + (size_t)(m0 + w * 16 + srow) * 256 + (kk) + scol,       \
                    (char*)(Xdst) + w * 1024);                                   \
    } while (0)

    QSTAGE(Wbuf[0], Xbuf[0], 0);
    asm volatile("s_waitcnt vmcnt(0)" ::: "memory");
    __builtin_amdgcn_s_barrier();

    #pragma unroll
    for (int t = 0; t < 8; ++t) {
        ushort* Wc = Wbuf[t & 1];
        ushort* Xc = Xbuf[t & 1];
        if (t < 7) QSTAGE(Wbuf[(t + 1) & 1], Xbuf[(t + 1) & 1], (t + 1) * 32);
        bf16x8 af[4], bfr[4];
        #pragma unroll
        for (int i = 0; i < 4; ++i)
            af[i] = *(const bf16x8*)(Wc + (w * 64 + i * 16 + lj) * 32 + xsl);
        #pragma unroll
        for (int j = 0; j < 4; ++j)
            bfr[j] = *(const bf16x8*)(Xc + (j * 16 + lj) * 32 + xsl);
        #pragma unroll
        for (int i = 0; i < 4; ++i)
            #pragma unroll
            for (int j = 0; j < 4; ++j)
                acc[i][j] = __builtin_amdgcn_mfma_f32_16x16x32_bf16(af[i], bfr[j], acc[i][j], 0, 0, 0);
        asm volatile("s_waitcnt vmcnt(0)" ::: "memory");
        __builtin_amdgcn_s_barrier();
    }
    #undef QSTAGE

    // ---- epilogue stage 1: acc -> LDS tile T[ml 0..63][el 0..255], swizzled ----
    uint* T = (uint*)S;   // 32KB overlay
    #pragma unroll
    for (int i = 0; i < 4; ++i) {
        const int el0 = w * 64 + i * 16 + lg * 4;   // 4 consecutive e
        #pragma unroll
        for (int j = 0; j < 4; ++j) {
            const int ml = j * 16 + lj;
            union { ushort u[4]; uint2 v; } pk;
            if (seg == 3) {
                #pragma unroll
                for (int r = 0; r < 4; ++r) {
                    const float z = acc[i][j][r] + gbias[el0 + r];
                    pk.u[r] = f2bf(1.f / (1.f + __expf(-z)));
                }
            } else {
                #pragma unroll
                for (int r = 0; r < 4; ++r) pk.u[r] = f2bf(acc[i][j][r]);
            }
            const int wd = (ml * 128 + (el0 >> 1)) ^ ((ml & 7) << 2);
            *(uint2*)(T + wd) = pk.v;
        }
    }
    __syncthreads();

    // ---- epilogue stage 2: LDS -> global, coalesced ----
    const int b2 = m0 >> 8;
    const int n0 = m0 & 255;
    if (seg < 3) {
        ushort* base = (seg == 0) ? q_ws : (seg == 1) ? k_ws : v_ws;
        #pragma unroll
        for (int hh = 0; hh < 2; ++hh) {
            const int h = w * 2 + hh;
            ushort* gdst = base + ((size_t)(b2 * 8 + h) * 256 + n0) * 32;
            #pragma unroll
            for (int it = 0; it < 4; ++it) {
                const int ml = it * 16 + (lane >> 2);
                const int cq = lane & 3;
                const int wd = (ml * 128 + h * 16 + cq * 4) ^ ((ml & 7) << 2);
                const uint4 d = *(const uint4*)(T + wd);
                *(uint4*)(gdst + (size_t)ml * 32 + cq * 8) = d;
            }
        }
    } else {
        const int row  = tid >> 2;
        const int part = tid & 3;
        ushort* gdst = g_ws + (size_t)(m0 + row) * 256;
        #pragma unroll
        for (int r8 = 0; r8 < 8; ++r8) {
            const int wc = r8 * 16 + part * 4;
            const int wd = (row * 128 + wc) ^ ((row & 7) << 2);
            const uint4 d = *(const uint4*)(T + wd);
            *(uint4*)(gdst + wc * 2) = d;
        }
    }
}

// ---------------- Kernel 2: MFMA attention (unchanged) ----------------
#define SWZ(c) ((((c) >> 2) & 3) << 5)

__global__ __launch_bounds__(512) void attn_mfma_kernel(
    const ushort* __restrict__ q_ws,
    const ushort* __restrict__ k_ws,
    const ushort* __restrict__ v_ws,
    const ushort* __restrict__ g_ws,
    const float* __restrict__ bias,   // [8][256][256]
    const float* __restrict__ mask,   // [128][256]
    ushort* __restrict__ wa_ws)       // bf16 [32768][256]
{
    __shared__ ushort Ks[256 * 32];
    __shared__ ushort Vt[32 * 256];
    __shared__ ushort Pl[8 * 16 * 64];

    const int tid  = threadIdx.x;
    const int bh   = blockIdx.x >> 1;
    const int half = blockIdx.x & 1;
    const int b2   = bh >> 3;
    const int h    = bh & 7;
    const int w    = tid >> 6;
    const int lane = tid & 63;
    const int lj   = lane & 15;
    const int lg   = lane >> 4;

    {
        const char* gk = (const char*)(k_ws + (size_t)bh * 8192);
        gload_lds16(gk + tid * 16,        (char*)Ks + w * 1024);
        gload_lds16(gk + 8192 + tid * 16, (char*)Ks + 8192 + w * 1024);
    }
    {
        const int cq = tid & 3;
        #pragma unroll
        for (int it = 0; it < 2; ++it) {
            const int n = it * 128 + (tid >> 2);
            uint4 v = *(const uint4*)(v_ws + (size_t)bh * 8192 + n * 32 + cq * 8);
            const ushort* pv = (const ushort*)&v;
            #pragma unroll
            for (int e = 0; e < 8; ++e) {
                const int c = cq * 8 + e;
                const int byte = c * 512 + ((2 * n) ^ SWZ(c));
                Vt[byte >> 1] = pv[e];
            }
        }
    }

    const int q0 = half * 128 + w * 16;
    const bf16x8 qf = *(const bf16x8*)(q_ws + (size_t)bh * 8192 + (size_t)(q0 + lj) * 32 + lg * 8);

    f32x4 acc[16];
    const float* bbase = bias + (size_t)h * 256 * 256;
    const float* mrow  = mask + (size_t)b2 * 256;
    #pragma unroll
    for (int t = 0; t < 16; ++t) {
        const int col = t * 16 + lj;
        const float mterm = (mrow[col] - 1.0f) * 1e9f;
        #pragma unroll
        for (int r = 0; r < 4; ++r) {
            const int qrow = q0 + lg * 4 + r;
            acc[t][r] = bbase[(size_t)qrow * 256 + col] + mterm;
        }
    }

    __syncthreads();

    #pragma unroll
    for (int t = 0; t < 16; ++t) {
        const bf16x8 kf = *(const bf16x8*)(Ks + (t * 16 + lj) * 32 + lg * 8);
        acc[t] = __builtin_amdgcn_mfma_f32_16x16x32_bf16(qf, kf, acc[t], 0, 0, 0);
    }

    float inv[4];
    #pragma unroll
    for (int r = 0; r < 4; ++r) {
        float m = acc[0][r];
        #pragma unroll
        for (int t = 1; t < 16; ++t) m = fmaxf(m, acc[t][r]);
        m = fmaxf(m, __shfl_xor(m, 1));
        m = fmaxf(m, __shfl_xor(m, 2));
        m = fmaxf(m, __shfl_xor(m, 4));
        m = fmaxf(m, __shfl_xor(m, 8));
        float s = 0.f;
        #pragma unroll
        for (int t = 0; t < 16; ++t) {
            float e = __expf(acc[t][r] - m);
            acc[t][r] = e;
            s += e;
        }
        s += __shfl_xor(s, 1);
        s += __shfl_xor(s, 2);
        s += __shfl_xor(s, 4);
        s += __shfl_xor(s, 8);
        inv[r] = 1.0f / s;
    }

    ushort* PlW = Pl + w * 1024;
    f32x4 o0 = {0.f, 0.f, 0.f, 0.f};
    f32x4 o1 = {0.f, 0.f, 0.f, 0.f};
    #pragma unroll
    for (int ch = 0; ch < 4; ++ch) {
        #pragma unroll
        for (int tt = 0; tt < 4; ++tt) {
            const int t = ch * 4 + tt;
            #pragma unroll
            for (int r = 0; r < 4; ++r) {
                const int row  = lg * 4 + r;
                const int byte = row * 128 + ((32 * tt + 2 * lj) ^ (lg << 5));
                PlW[byte >> 1] = f2bf(acc[t][r]);
            }
        }
        #pragma unroll
        for (int kk = 0; kk < 2; ++kk) {
            const int abyte = lj * 128 + ((64 * kk + 16 * lg) ^ SWZ(lj));
            const bf16x8 pa = *(const bf16x8*)(PlW + (abyte >> 1));
            const int ks = ch * 2 + kk;
            {
                const int cr = lj;
                const int vbyte = cr * 512 + ((64 * ks + 16 * lg) ^ SWZ(cr));
                const bf16x8 vb = *(const bf16x8*)(Vt + (vbyte >> 1));
                o0 = __builtin_amdgcn_mfma_f32_16x16x32_bf16(pa, vb, o0, 0, 0, 0);
            }
            {
                const int cr = 16 + lj;
                const int vbyte = cr * 512 + ((64 * ks + 16 * lg) ^ SWZ(cr));
                const bf16x8 vb = *(const bf16x8*)(Vt + (vbyte >> 1));
                o1 = __builtin_amdgcn_mfma_f32_16x16x32_bf16(pa, vb, o1, 0, 0, 0);
            }
        }
    }

    #pragma unroll
    for (int r = 0; r < 4; ++r) {
        const int qrow = q0 + lg * 4 + r;
        const size_t rowbase = ((size_t)(b2 * 256 + qrow)) * 256 + h * 32;
        {
            const float gv = bf2f(g_ws[rowbase + lj]);
            wa_ws[rowbase + lj] = f2bf(o0[r] * inv[r] * gv);
        }
        {
            const float gv = bf2f(g_ws[rowbase + 16 + lj]);
            wa_ws[rowbase + 16 + lj] = f2bf(o1[r] * inv[r] * gv);
        }
    }
}

// ---------------- Kernel 3: MFMA output projection, seg-tile ----------------
// Tile: 64 m-rows x 256 o-cols (full output width). Wo L2-hot; WA read once.
// A=WA(m rows), B=Wo(o rows); D col = o -> full-line fp32 stores.
__global__ __launch_bounds__(256) void out_mfma_kernel(
    const ushort* __restrict__ WA,   // bf16 [32768][256]
    const ushort* __restrict__ Wob,  // bf16 [256][256]
    const float* __restrict__ bo,    // [256]
    float* __restrict__ out)         // [32768][256]
{
    __shared__ ushort S[20480];      // Wobuf0(8192) WAbuf0(2048) Wobuf1 WAbuf1
    ushort* const Obuf[2] = { S,        S + 10240 };
    ushort* const Abuf[2] = { S + 8192, S + 18432 };

    const int tid  = threadIdx.x;
    const int w    = tid >> 6;       // o-quadrant w*64
    const int lane = tid & 63;
    const int lj   = lane & 15;
    const int lg   = lane >> 4;
    const int m0   = blockIdx.x * 64;

    f32x4 acc[4][4];
    #pragma unroll
    for (int i = 0; i < 4; ++i)
        #pragma unroll
        for (int j = 0; j < 4; ++j) acc[i][j] = (f32x4){0.f, 0.f, 0.f, 0.f};

    const int srow = lane >> 2;
    const int scol = (((lane & 3) ^ ((lane >> 3) & 3)) << 3);
    const int xsl  = ((lg ^ ((lj >> 1) & 3)) << 3);

    #define OSTAGE(Odst, Adst, kk) do {                                          \
        _Pragma("unroll")                                                        \
        for (int c = 0; c < 4; ++c) {                                            \
            const int ci = w * 4 + c;                                            \
            gload_lds16(Wob + (size_t)(ci * 16 + srow) * 256 + (kk) + scol,      \
                        (char*)(Odst) + ci * 1024);                              \
        }                                                                        \
        gload_lds16(WA + (size_t)(m0 + w * 16 + srow) * 256 + (kk) + scol,       \
                    (char*)(Adst) + w * 1024);                                   \
    } while (0)

    OSTAGE(Obuf[0], Abuf[0], 0);
    asm volatile("s_waitcnt vmcnt(0)" ::: "memory");
    __builtin_amdgcn_s_barrier();

    #pragma unroll
    for (int t = 0; t < 8; ++t) {
        ushort* Oc = Obuf[t & 1];
        ushort* Ac = Abuf[t & 1];
        if (t < 7) OSTAGE(Obuf[(t + 1) & 1], Abuf[(t + 1) & 1], (t + 1) * 32);
        bf16x8 af[4], bfr[4];
        #pragma unroll
        for (int i = 0; i < 4; ++i)    // A = WA m-rows (shared across waves)
            af[i] = *(const bf16x8*)(Ac + (i * 16 + lj) * 32 + xsl);
        #pragma unroll
        for (int j = 0; j < 4; ++j)    // B = Wo o-rows (wave quadrant)
            bfr[j] = *(const bf16x8*)(Oc + (w * 64 + j * 16 + lj) * 32 + xsl);
        #pragma unroll
        for (int i = 0; i < 4; ++i)
            #pragma unroll
            for (int j = 0; j < 4; ++j)
                acc[i][j] = __builtin_amdgcn_mfma_f32_16x16x32_bf16(af[i], bfr[j], acc[i][j], 0, 0, 0);
        asm volatile("s_waitcnt vmcnt(0)" ::: "memory");
        __builtin_amdgcn_s_barrier();
    }
    #undef OSTAGE

    // D row = m (i,lg,r), col = o (w,j,lj): full-line fp32 stores
    #pragma unroll
    for (int i = 0; i < 4; ++i) {
        #pragma unroll
        for (int r = 0; r < 4; ++r) {
            const int m = m0 + i * 16 + lg * 4 + r;
            #pragma unroll
            for (int j = 0; j < 4; ++j) {
                const int o = w * 64 + j * 16 + lj;
                out[(size_t)m * 256 + o] = acc[i][j][r] + bo[o];
            }
        }
    }
}

extern "C" void kernel_launch(void* const* d_in, const int* in_sizes, int n_in,
                              void* d_out, int out_size, void* d_ws, size_t ws_size,
                              hipStream_t stream) {
    const float* in_data = (const float*)d_in[0];
    const float* mask    = (const float*)d_in[1];
    const float* nb_bias = (const float*)d_in[2];
    const float* w_qkv   = (const float*)d_in[3];
    const float* w_gate  = (const float*)d_in[4];
    const float* g_bias  = (const float*)d_in[5];
    const float* w_o     = (const float*)d_in[6];
    const float* b_o     = (const float*)d_in[7];
    float* out = (float*)d_out;

    ushort* ws = (ushort*)d_ws;
    const size_t per_head = (size_t)B2 * NHEAD * NSEQ * CDIM;  // 8,388,608
    ushort* q_ws   = ws;
    ushort* k_ws   = q_ws + per_head;
    ushort* v_ws   = k_ws + per_head;
    ushort* g_ws   = v_ws + per_head;                 // [32768][256]
    ushort* wa_ws  = g_ws + (size_t)NROWS * HC;
    ushort* xb     = wa_ws + (size_t)NROWS * HC;      // [32768][256]
    ushort* wqkvgb = xb + (size_t)NROWS * DMODEL;     // [1024][256]
    ushort* wob    = wqkvgb + 1024 * 256;             // [256][256]

    convert_kernel<<<dim3(2048), 256, 0, stream>>>(
        in_data, w_qkv, w_gate, w_o, xb, wqkvgb, wob);

    qkvg_mfma_kernel<<<dim3(NROWS / 64, 4), 256, 0, stream>>>(
        xb, wqkvgb, g_bias, q_ws, k_ws, v_ws, g_ws);

    attn_mfma_kernel<<<dim3(B2 * NHEAD * 2), 512, 0, stream>>>(
        q_ws, k_ws, v_ws, g_ws, nb_bias, mask, wa_ws);

    out_mfma_kernel<<<dim3(NROWS / 64), 256, 0, stream>>>(
        wa_ws, wob, b_o, out);
}